// Round 3
// baseline (1560.170 us; speedup 1.0000x reference)
//
#include <hip/hip_runtime.h>

#define N_NODES 50000
#define N_EDGES 1600000
#define DIM 128
#define LN_EPS 1e-10f

#define ROWS_PER_BUCKET 64
#define N_BUCKETS ((N_NODES + ROWS_PER_BUCKET - 1) / ROWS_PER_BUCKET)  // 782
#define BUCKET_CAP 2560   // mean 2048, sigma ~45 -> +11 sigma, never overflows
#define EPB 4096          // edges per scatter block

// ---------------------------------------------------------------------------
// Bucket scatter: bin edges by row>>6 into fixed-capacity buckets.
// Per block: LDS histogram -> one global atomic per (block,bucket) reserving a
// contiguous run -> write edges into the run.  Same-line perm writes now come
// from one block back-to-back, so L2 coalesces them (vs R2's 101 MB of
// single-entry line evictions).  Packed entry: (col | row_local<<16, val).
// ---------------------------------------------------------------------------
__global__ __launch_bounds__(256) void bucket_scatter(
    const int* __restrict__ rows, const int* __restrict__ cols,
    const float* __restrict__ vals, int* __restrict__ gcnt,
    int2* __restrict__ perm)
{
    __shared__ int cnt[N_BUCKETS];
    __shared__ int gbase[N_BUCKETS];
    __shared__ int lcur[N_BUCKETS];
    const int t = threadIdx.x;
    for (int i = t; i < N_BUCKETS; i += 256) { cnt[i] = 0; lcur[i] = 0; }
    __syncthreads();

    const int base = blockIdx.x * EPB;
    for (int k = 0; k < EPB; k += 256) {
        int e = base + k + t;
        if (e < N_EDGES) atomicAdd(&cnt[rows[e] >> 6], 1);
    }
    __syncthreads();

    for (int i = t; i < N_BUCKETS; i += 256) {
        int c = cnt[i];
        gbase[i] = c ? atomicAdd(&gcnt[i], c) : 0;
    }
    __syncthreads();

    for (int k = 0; k < EPB; k += 256) {
        int e = base + k + t;
        if (e < N_EDGES) {
            int r = rows[e];
            int b = r >> 6;
            int rank = atomicAdd(&lcur[b], 1);
            int pos = gbase[b] + rank;
            if (pos < BUCKET_CAP)   // statistically impossible; safety only
                perm[(size_t)b * BUCKET_CAP + pos] =
                    make_int2(cols[e] | ((r & 63) << 16), __float_as_int(vals[e]));
        }
    }
}

// ---------------------------------------------------------------------------
// Bucket aggregate: one block per bucket (64 rows).  32 KB LDS accumulator,
// ds_add_f32 (lane & lane+64 layout -> 2-way bank alias = free), coalesced
// float4 writeback.  No global fp32 atomics.
// ---------------------------------------------------------------------------
__global__ __launch_bounds__(256) void bucket_aggregate(
    const int2* __restrict__ perm, const int* __restrict__ gcnt,
    const float* __restrict__ feat, float* __restrict__ aggr)
{
    __shared__ float acc[ROWS_PER_BUCKET * DIM];  // 32 KB
    const int b = blockIdx.x;
    const int t = threadIdx.x;
    for (int i = t; i < ROWS_PER_BUCKET * DIM; i += 256) acc[i] = 0.0f;
    __syncthreads();

    int n = gcnt[b];
    if (n > BUCKET_CAP) n = BUCKET_CAP;
    const int lane = t & 63;
    const int wid  = t >> 6;
    const int2* pb = perm + (size_t)b * BUCKET_CAP;

    int e = wid;
    for (; e + 4 < n; e += 8) {   // 2 edges in flight per wave for MLP
        int2 p0 = pb[e];
        int2 p1 = pb[e + 4];
        int c0 = p0.x & 0xFFFF, r0 = p0.x >> 16;
        int c1 = p1.x & 0xFFFF, r1 = p1.x >> 16;
        float v0 = __int_as_float(p0.y);
        float v1 = __int_as_float(p1.y);
        float a0 = feat[(size_t)c0 * DIM + lane];
        float b0 = feat[(size_t)c0 * DIM + lane + 64];
        float a1 = feat[(size_t)c1 * DIM + lane];
        float b1 = feat[(size_t)c1 * DIM + lane + 64];
        atomicAdd(&acc[r0 * DIM + lane],      v0 * a0);
        atomicAdd(&acc[r0 * DIM + lane + 64], v0 * b0);
        atomicAdd(&acc[r1 * DIM + lane],      v1 * a1);
        atomicAdd(&acc[r1 * DIM + lane + 64], v1 * b1);
    }
    for (; e < n; e += 4) {
        int2 p = pb[e];
        int c = p.x & 0xFFFF, rl = p.x >> 16;
        float v = __int_as_float(p.y);
        float ga = feat[(size_t)c * DIM + lane];
        float gb = feat[(size_t)c * DIM + lane + 64];
        atomicAdd(&acc[rl * DIM + lane],      v * ga);
        atomicAdd(&acc[rl * DIM + lane + 64], v * gb);
    }
    __syncthreads();

    const int row0 = b * ROWS_PER_BUCKET;
    for (int i = t; i < ROWS_PER_BUCKET * DIM / 4; i += 256) {
        int r = row0 + (i >> 5);
        if (r < N_NODES)
            ((float4*)aggr)[(size_t)r * 32 + (i & 31)] = ((const float4*)acc)[i];
    }
}

// ---------------------------------------------------------------------------
// Fused  out = LN(ReLU(aggr @ W^T + b)) * scale + offset.  One wave per node.
// ---------------------------------------------------------------------------
__global__ __launch_bounds__(256) void gemm_relu_ln(
    const float* __restrict__ aggr, const float* __restrict__ W,
    const float* __restrict__ bias, const float* __restrict__ scale,
    const float* __restrict__ offset, float* __restrict__ out)
{
    __shared__ float sWt[DIM * 129];  // sWt[i*129 + o] = W[o][i]

    for (int idx = threadIdx.x; idx < DIM * DIM; idx += 256) {
        int o = idx >> 7;
        int i = idx & 127;
        sWt[i * 129 + o] = W[idx];
    }
    __syncthreads();

    const int lane = threadIdx.x & 63;
    const int wid  = threadIdx.x >> 6;

    const float b0 = bias[lane],    b1 = bias[lane + 64];
    const float s0 = scale[lane],   s1 = scale[lane + 64];
    const float f0 = offset[lane],  f1 = offset[lane + 64];

    for (int n = blockIdx.x * 4 + wid; n < N_NODES; n += gridDim.x * 4) {
        int nu = __builtin_amdgcn_readfirstlane(n);
        const float* arow = aggr + (size_t)nu * DIM;

        float acc0 = b0, acc1 = b1;
        #pragma unroll 8
        for (int i = 0; i < DIM; ++i) {
            float a = arow[i];
            acc0 = fmaf(a, sWt[i * 129 + lane], acc0);
            acc1 = fmaf(a, sWt[i * 129 + lane + 64], acc1);
        }

        float a0 = fmaxf(acc0, 0.0f);
        float a1 = fmaxf(acc1, 0.0f);

        float s = a0 + a1;
        #pragma unroll
        for (int off = 32; off >= 1; off >>= 1) s += __shfl_xor(s, off, 64);
        float mean = s * (1.0f / 128.0f);

        float d0 = a0 - mean, d1 = a1 - mean;
        float q = d0 * d0 + d1 * d1;
        #pragma unroll
        for (int off = 32; off >= 1; off >>= 1) q += __shfl_xor(q, off, 64);
        float rstd = rsqrtf(q * (1.0f / 128.0f) + LN_EPS);

        out[(size_t)n * DIM + lane]      = d0 * s0 * rstd + f0;
        out[(size_t)n * DIM + lane + 64] = d1 * s1 * rstd + f1;
    }
}

extern "C" void kernel_launch(void* const* d_in, const int* in_sizes, int n_in,
                              void* d_out, int out_size, void* d_ws, size_t ws_size,
                              hipStream_t stream) {
    const float* feat_in = (const float*)d_in[0];
    const int*   rows    = (const int*)d_in[1];
    const int*   cols    = (const int*)d_in[2];
    const float* vals    = (const float*)d_in[3];
    const float* W       = (const float*)d_in[4];
    const float* bias    = (const float*)d_in[5];
    const float* scale   = (const float*)d_in[6];
    const float* offset  = (const float*)d_in[7];
    float* out = (float*)d_out;

    // ---- workspace layout ----
    char* p = (char*)d_ws;
    float* aggr = (float*)p;   p += (size_t)N_NODES * DIM * 4;            // 25.6 MB
    int2*  perm = (int2*)p;    p += (size_t)N_BUCKETS * BUCKET_CAP * 8;   // 16.0 MB
    int*   gcnt = (int*)p;     p += ((size_t)N_BUCKETS + 64) * 4;

    hipMemsetAsync(gcnt, 0, (size_t)N_BUCKETS * sizeof(int), stream);

    int sb = (N_EDGES + EPB - 1) / EPB;  // 391
    bucket_scatter  <<<sb, 256, 0, stream>>>(rows, cols, vals, gcnt, perm);
    bucket_aggregate<<<N_BUCKETS, 256, 0, stream>>>(perm, gcnt, feat_in, aggr);
    gemm_relu_ln    <<<1024, 256, 0, stream>>>(aggr, W, bias, scale, offset, out);
}

// Round 4
// 389.572 us; speedup vs baseline: 4.0048x; 4.0048x over previous
//
#include <hip/hip_runtime.h>

#define N_NODES 50000
#define N_EDGES 1600000
#define DIM 128
#define LN_EPS 1e-10f

#define ROWS_PER_BUCKET 64
#define N_BUCKETS ((N_NODES + ROWS_PER_BUCKET - 1) / ROWS_PER_BUCKET)  // 782
#define BUCKET_CAP 2560   // mean 2048, sigma ~45 -> +11 sigma
#define EPB 4096          // edges per scatter block
#define CAPR 80           // per-row list cap: mean 32, Poisson sigma 5.7 -> +8.4 sigma

// ---------------------------------------------------------------------------
// Bucket scatter: bin edges by row>>6 into fixed-capacity buckets.
// Per block: LDS histogram -> one global atomic per (block,bucket) reserving a
// contiguous run -> write edges into the run.  Contiguous runs => L2 write
// combining (vs exact-CSR scatter's 101 MB of single-entry line evictions).
// Packed entry: (col | row_local<<16, val).
// ---------------------------------------------------------------------------
__global__ __launch_bounds__(256) void bucket_scatter(
    const int* __restrict__ rows, const int* __restrict__ cols,
    const float* __restrict__ vals, int* __restrict__ gcnt,
    int2* __restrict__ perm)
{
    __shared__ int cnt[N_BUCKETS];
    __shared__ int gbase[N_BUCKETS];
    __shared__ int lcur[N_BUCKETS];
    const int t = threadIdx.x;
    for (int i = t; i < N_BUCKETS; i += 256) { cnt[i] = 0; lcur[i] = 0; }
    __syncthreads();

    const int base = blockIdx.x * EPB;
    for (int k = 0; k < EPB; k += 256) {
        int e = base + k + t;
        if (e < N_EDGES) atomicAdd(&cnt[rows[e] >> 6], 1);
    }
    __syncthreads();

    for (int i = t; i < N_BUCKETS; i += 256) {
        int c = cnt[i];
        gbase[i] = c ? atomicAdd(&gcnt[i], c) : 0;
    }
    __syncthreads();

    for (int k = 0; k < EPB; k += 256) {
        int e = base + k + t;
        if (e < N_EDGES) {
            int r = rows[e];
            int b = r >> 6;
            int rank = atomicAdd(&lcur[b], 1);
            int pos = gbase[b] + rank;
            if (pos < BUCKET_CAP)   // statistically impossible; safety only
                perm[(size_t)b * BUCKET_CAP + pos] =
                    make_int2(cols[e] | ((r & 63) << 16), __float_as_int(vals[e]));
        }
    }
}

// ---------------------------------------------------------------------------
// Aggregate v2: one block per bucket.  Phase 1: compact entries into 64
// per-row LDS lists (atomics spread over 64 counters, one pass, coalesced
// perm reads).  Phase 2: each wave aggregates 16 rows sequentially with
// register accumulators (float2/lane) and unroll-4 gather ILP; one coalesced
// 512B store per row.  No LDS atomics in the hot loop, no global atomics.
// ---------------------------------------------------------------------------
__global__ __launch_bounds__(256) void bucket_aggregate2(
    const int2* __restrict__ perm, const int* __restrict__ gcnt,
    const float* __restrict__ feat, float* __restrict__ aggr)
{
    __shared__ int  lcnt[ROWS_PER_BUCKET];
    __shared__ int2 lists[ROWS_PER_BUCKET * CAPR];   // 40 KB
    const int b = blockIdx.x;
    const int t = threadIdx.x;
    if (t < ROWS_PER_BUCKET) lcnt[t] = 0;
    __syncthreads();

    int n = gcnt[b];
    if (n > BUCKET_CAP) n = BUCKET_CAP;
    const int2* pb = perm + (size_t)b * BUCKET_CAP;

    for (int e = t; e < n; e += 256) {
        int2 p = pb[e];                       // coalesced 2KB/wavefront-pass
        int rl = (p.x >> 16) & 63;
        int pos = atomicAdd(&lcnt[rl], 1);
        if (pos < CAPR)
            lists[rl * CAPR + pos] = make_int2(p.x & 0xFFFF, p.y);
    }
    __syncthreads();

    const int lane = t & 63;
    const int wid  = t >> 6;

    for (int i = 0; i < 16; ++i) {
        int rl = wid * 16 + i;
        int r  = b * ROWS_PER_BUCKET + rl;
        if (r >= N_NODES) break;
        int cnt = lcnt[rl];
        if (cnt > CAPR) cnt = CAPR;
        const int2* L = &lists[rl * CAPR];

        float ax = 0.0f, ay = 0.0f;
        int e = 0;
        for (; e + 3 < cnt; e += 4) {
            int2 p0 = L[e], p1 = L[e + 1], p2 = L[e + 2], p3 = L[e + 3];
            float2 g0 = ((const float2*)(feat + (size_t)p0.x * DIM))[lane];
            float2 g1 = ((const float2*)(feat + (size_t)p1.x * DIM))[lane];
            float2 g2 = ((const float2*)(feat + (size_t)p2.x * DIM))[lane];
            float2 g3 = ((const float2*)(feat + (size_t)p3.x * DIM))[lane];
            float v0 = __int_as_float(p0.y), v1 = __int_as_float(p1.y);
            float v2 = __int_as_float(p2.y), v3 = __int_as_float(p3.y);
            ax = fmaf(v0, g0.x, ax);  ay = fmaf(v0, g0.y, ay);
            ax = fmaf(v1, g1.x, ax);  ay = fmaf(v1, g1.y, ay);
            ax = fmaf(v2, g2.x, ax);  ay = fmaf(v2, g2.y, ay);
            ax = fmaf(v3, g3.x, ax);  ay = fmaf(v3, g3.y, ay);
        }
        for (; e < cnt; ++e) {
            int2 p = L[e];
            float2 g = ((const float2*)(feat + (size_t)p.x * DIM))[lane];
            float v = __int_as_float(p.y);
            ax = fmaf(v, g.x, ax);  ay = fmaf(v, g.y, ay);
        }
        ((float2*)(aggr + (size_t)r * DIM))[lane] = make_float2(ax, ay);
    }
}

// ---------------------------------------------------------------------------
// Fused  out = LN(ReLU(aggr @ W^T + b)) * scale + offset.  One wave per node.
// ---------------------------------------------------------------------------
__global__ __launch_bounds__(256) void gemm_relu_ln(
    const float* __restrict__ aggr, const float* __restrict__ W,
    const float* __restrict__ bias, const float* __restrict__ scale,
    const float* __restrict__ offset, float* __restrict__ out)
{
    __shared__ float sWt[DIM * 129];  // sWt[i*129 + o] = W[o][i]

    for (int idx = threadIdx.x; idx < DIM * DIM; idx += 256) {
        int o = idx >> 7;
        int i = idx & 127;
        sWt[i * 129 + o] = W[idx];
    }
    __syncthreads();

    const int lane = threadIdx.x & 63;
    const int wid  = threadIdx.x >> 6;

    const float b0 = bias[lane],    b1 = bias[lane + 64];
    const float s0 = scale[lane],   s1 = scale[lane + 64];
    const float f0 = offset[lane],  f1 = offset[lane + 64];

    for (int n = blockIdx.x * 4 + wid; n < N_NODES; n += gridDim.x * 4) {
        int nu = __builtin_amdgcn_readfirstlane(n);
        const float* arow = aggr + (size_t)nu * DIM;

        float acc0 = b0, acc1 = b1;
        #pragma unroll 8
        for (int i = 0; i < DIM; ++i) {
            float a = arow[i];
            acc0 = fmaf(a, sWt[i * 129 + lane], acc0);
            acc1 = fmaf(a, sWt[i * 129 + lane + 64], acc1);
        }

        float a0 = fmaxf(acc0, 0.0f);
        float a1 = fmaxf(acc1, 0.0f);

        float s = a0 + a1;
        #pragma unroll
        for (int off = 32; off >= 1; off >>= 1) s += __shfl_xor(s, off, 64);
        float mean = s * (1.0f / 128.0f);

        float d0 = a0 - mean, d1 = a1 - mean;
        float q = d0 * d0 + d1 * d1;
        #pragma unroll
        for (int off = 32; off >= 1; off >>= 1) q += __shfl_xor(q, off, 64);
        float rstd = rsqrtf(q * (1.0f / 128.0f) + LN_EPS);

        out[(size_t)n * DIM + lane]      = d0 * s0 * rstd + f0;
        out[(size_t)n * DIM + lane + 64] = d1 * s1 * rstd + f1;
    }
}

extern "C" void kernel_launch(void* const* d_in, const int* in_sizes, int n_in,
                              void* d_out, int out_size, void* d_ws, size_t ws_size,
                              hipStream_t stream) {
    const float* feat_in = (const float*)d_in[0];
    const int*   rows    = (const int*)d_in[1];
    const int*   cols    = (const int*)d_in[2];
    const float* vals    = (const float*)d_in[3];
    const float* W       = (const float*)d_in[4];
    const float* bias    = (const float*)d_in[5];
    const float* scale   = (const float*)d_in[6];
    const float* offset  = (const float*)d_in[7];
    float* out = (float*)d_out;

    // ---- workspace layout ----
    char* p = (char*)d_ws;
    float* aggr = (float*)p;   p += (size_t)N_NODES * DIM * 4;            // 25.6 MB
    int2*  perm = (int2*)p;    p += (size_t)N_BUCKETS * BUCKET_CAP * 8;   // 16.0 MB
    int*   gcnt = (int*)p;     p += ((size_t)N_BUCKETS + 64) * 4;

    hipMemsetAsync(gcnt, 0, (size_t)N_BUCKETS * sizeof(int), stream);

    int sb = (N_EDGES + EPB - 1) / EPB;  // 391
    bucket_scatter   <<<sb, 256, 0, stream>>>(rows, cols, vals, gcnt, perm);
    bucket_aggregate2<<<N_BUCKETS, 256, 0, stream>>>(perm, gcnt, feat_in, aggr);
    gemm_relu_ln     <<<1024, 256, 0, stream>>>(aggr, W, bias, scale, offset, out);
}

// Round 5
// 289.075 us; speedup vs baseline: 5.3971x; 1.3477x over previous
//
#include <hip/hip_runtime.h>

#define N_NODES 50000
#define N_EDGES 1600000
#define DIM 128
#define LN_EPS 1e-10f

#define ROWS_PER_BUCKET 64
#define N_BUCKETS ((N_NODES + ROWS_PER_BUCKET - 1) / ROWS_PER_BUCKET)  // 782
#define BUCKET_CAP 2560   // mean 2048, sigma ~45 -> +11 sigma
#define EPB 4096          // edges per scatter block

#define SLICES 4          // aggregate blocks per bucket
#define ROWS_PER_AGG 16   // rows per aggregate block
#define AGG_CAP 768       // entries per 16-row slice: mean 512, sigma 22 -> +11 sigma

// ---------------------------------------------------------------------------
// Bucket scatter: bin edges by row>>6 into fixed-capacity buckets.
// Per block: LDS histogram -> one global atomic per (block,bucket) reserving a
// contiguous run -> write edges into the run (L2 write combining).
// Packed entry: (col | row_local<<16, val).
// ---------------------------------------------------------------------------
__global__ __launch_bounds__(256) void bucket_scatter(
    const int* __restrict__ rows, const int* __restrict__ cols,
    const float* __restrict__ vals, int* __restrict__ gcnt,
    int2* __restrict__ perm)
{
    __shared__ int cnt[N_BUCKETS];
    __shared__ int gbase[N_BUCKETS];
    __shared__ int lcur[N_BUCKETS];
    const int t = threadIdx.x;
    for (int i = t; i < N_BUCKETS; i += 256) { cnt[i] = 0; lcur[i] = 0; }
    __syncthreads();

    const int base = blockIdx.x * EPB;
    for (int k = 0; k < EPB; k += 256) {
        int e = base + k + t;
        if (e < N_EDGES) atomicAdd(&cnt[rows[e] >> 6], 1);
    }
    __syncthreads();

    for (int i = t; i < N_BUCKETS; i += 256) {
        int c = cnt[i];
        gbase[i] = c ? atomicAdd(&gcnt[i], c) : 0;
    }
    __syncthreads();

    for (int k = 0; k < EPB; k += 256) {
        int e = base + k + t;
        if (e < N_EDGES) {
            int r = rows[e];
            int b = r >> 6;
            int rank = atomicAdd(&lcur[b], 1);
            int pos = gbase[b] + rank;
            if (pos < BUCKET_CAP)   // statistically impossible; safety only
                perm[(size_t)b * BUCKET_CAP + pos] =
                    make_int2(cols[e] | ((r & 63) << 16), __float_as_int(vals[e]));
        }
    }
}

// ---------------------------------------------------------------------------
// Aggregate v3: SLICES blocks per bucket, each owning 16 rows.  R4 was
// grid-limited (782 blocks = 3/CU = 12 waves/CU); this gives 3128 blocks and
// 6.4 KB LDS -> ~28 waves/CU resident, 2.3x the outstanding gathers.
// Phase 1: count + serial 16-scan + compact into one flat list (2 coalesced
// passes over the bucket).  Phase 2: each wave aggregates 4 rows with
// register accumulators and unroll-4 gather ILP; 512B store per row.
// ---------------------------------------------------------------------------
__global__ __launch_bounds__(256) void bucket_aggregate3(
    const int2* __restrict__ perm, const int* __restrict__ gcnt,
    const float* __restrict__ feat, float* __restrict__ aggr)
{
    __shared__ int  lcnt[ROWS_PER_AGG];
    __shared__ int  rowoff[ROWS_PER_AGG];
    __shared__ int  cursor[ROWS_PER_AGG];
    __shared__ int2 lists[AGG_CAP];          // 6 KB
    const int b     = blockIdx.x >> 2;       // bucket
    const int slice = blockIdx.x & 3;
    const int t = threadIdx.x;
    if (t < ROWS_PER_AGG) lcnt[t] = 0;
    __syncthreads();

    int n = gcnt[b];
    if (n > BUCKET_CAP) n = BUCKET_CAP;
    const int2* pb = perm + (size_t)b * BUCKET_CAP;
    const int lo = slice * ROWS_PER_AGG;

    for (int e = t; e < n; e += 256) {
        int rl = ((pb[e].x >> 16) & 63) - lo;
        if ((unsigned)rl < ROWS_PER_AGG) atomicAdd(&lcnt[rl], 1);
    }
    __syncthreads();
    if (t == 0) {
        int s = 0;
        #pragma unroll
        for (int i = 0; i < ROWS_PER_AGG; ++i) { rowoff[i] = s; cursor[i] = s; s += lcnt[i]; }
    }
    __syncthreads();
    for (int e = t; e < n; e += 256) {
        int2 p = pb[e];
        int rl = ((p.x >> 16) & 63) - lo;
        if ((unsigned)rl < ROWS_PER_AGG) {
            int pos = atomicAdd(&cursor[rl], 1);
            if (pos < AGG_CAP)
                lists[pos] = make_int2(p.x & 0xFFFF, p.y);
        }
    }
    __syncthreads();

    const int lane = t & 63;
    const int wid  = t >> 6;

    #pragma unroll
    for (int i = 0; i < 4; ++i) {
        int rl = wid * 4 + i;
        int r  = b * ROWS_PER_BUCKET + lo + rl;
        int cnt = lcnt[rl];
        int off = rowoff[rl];
        if (off + cnt > AGG_CAP) cnt = AGG_CAP - off;   // safety only
        const int2* L = &lists[off];

        float ax = 0.0f, ay = 0.0f;
        int e = 0;
        for (; e + 3 < cnt; e += 4) {
            int2 p0 = L[e], p1 = L[e + 1], p2 = L[e + 2], p3 = L[e + 3];
            float2 g0 = ((const float2*)(feat + (size_t)p0.x * DIM))[lane];
            float2 g1 = ((const float2*)(feat + (size_t)p1.x * DIM))[lane];
            float2 g2 = ((const float2*)(feat + (size_t)p2.x * DIM))[lane];
            float2 g3 = ((const float2*)(feat + (size_t)p3.x * DIM))[lane];
            float v0 = __int_as_float(p0.y), v1 = __int_as_float(p1.y);
            float v2 = __int_as_float(p2.y), v3 = __int_as_float(p3.y);
            ax = fmaf(v0, g0.x, ax);  ay = fmaf(v0, g0.y, ay);
            ax = fmaf(v1, g1.x, ax);  ay = fmaf(v1, g1.y, ay);
            ax = fmaf(v2, g2.x, ax);  ay = fmaf(v2, g2.y, ay);
            ax = fmaf(v3, g3.x, ax);  ay = fmaf(v3, g3.y, ay);
        }
        for (; e < cnt; ++e) {
            int2 p = L[e];
            float2 g = ((const float2*)(feat + (size_t)p.x * DIM))[lane];
            float v = __int_as_float(p.y);
            ax = fmaf(v, g.x, ax);  ay = fmaf(v, g.y, ay);
        }
        if (r < N_NODES)
            ((float2*)(aggr + (size_t)r * DIM))[lane] = make_float2(ax, ay);
    }
}

// ---------------------------------------------------------------------------
// Fused  out = LN(ReLU(aggr @ W^T + b)) * scale + offset.
// 4 nodes per wave per iteration: each LDS W-read feeds 8 FMAs (4x fewer
// LDS reads/node than the 1-node version).  aggr rows read as wave-uniform
// scalar loads.
// ---------------------------------------------------------------------------
__global__ __launch_bounds__(256) void gemm_relu_ln4(
    const float* __restrict__ aggr, const float* __restrict__ W,
    const float* __restrict__ bias, const float* __restrict__ scale,
    const float* __restrict__ offset, float* __restrict__ out)
{
    __shared__ float sWt[DIM * 129];  // sWt[i*129 + o] = W[o][i]

    for (int idx = threadIdx.x; idx < DIM * DIM; idx += 256) {
        int o = idx >> 7;
        int i = idx & 127;
        sWt[i * 129 + o] = W[idx];
    }
    __syncthreads();

    const int lane = threadIdx.x & 63;
    const int wid  = threadIdx.x >> 6;

    const float b0 = bias[lane],    b1 = bias[lane + 64];
    const float s0 = scale[lane],   s1 = scale[lane + 64];
    const float f0 = offset[lane],  f1 = offset[lane + 64];

    // 16 nodes per block-iteration (4 per wave); 50000 % 4 == 0.
    for (int g = blockIdx.x * 16 + wid * 4; g < N_NODES; g += gridDim.x * 16) {
        int nu = __builtin_amdgcn_readfirstlane(g);
        const float* A0 = aggr + (size_t)nu * DIM;
        const float* A1 = A0 + DIM;
        const float* A2 = A1 + DIM;
        const float* A3 = A2 + DIM;

        float x0 = b0, y0 = b1, x1 = b0, y1 = b1;
        float x2 = b0, y2 = b1, x3 = b0, y3 = b1;
        #pragma unroll 8
        for (int i = 0; i < DIM; ++i) {
            float w0 = sWt[i * 129 + lane];
            float w1 = sWt[i * 129 + lane + 64];
            float a0 = A0[i], a1 = A1[i], a2 = A2[i], a3 = A3[i];
            x0 = fmaf(a0, w0, x0);  y0 = fmaf(a0, w1, y0);
            x1 = fmaf(a1, w0, x1);  y1 = fmaf(a1, w1, y1);
            x2 = fmaf(a2, w0, x2);  y2 = fmaf(a2, w1, y2);
            x3 = fmaf(a3, w0, x3);  y3 = fmaf(a3, w1, y3);
        }

        #pragma unroll
        for (int j = 0; j < 4; ++j) {
            float a0 = (j == 0) ? x0 : (j == 1) ? x1 : (j == 2) ? x2 : x3;
            float a1 = (j == 0) ? y0 : (j == 1) ? y1 : (j == 2) ? y2 : y3;
            a0 = fmaxf(a0, 0.0f);
            a1 = fmaxf(a1, 0.0f);

            float s = a0 + a1;
            #pragma unroll
            for (int off = 32; off >= 1; off >>= 1) s += __shfl_xor(s, off, 64);
            float mean = s * (1.0f / 128.0f);

            float d0 = a0 - mean, d1 = a1 - mean;
            float q = d0 * d0 + d1 * d1;
            #pragma unroll
            for (int off = 32; off >= 1; off >>= 1) q += __shfl_xor(q, off, 64);
            float rstd = rsqrtf(q * (1.0f / 128.0f) + LN_EPS);

            size_t rowp = (size_t)(nu + j) * DIM;
            out[rowp + lane]      = d0 * s0 * rstd + f0;
            out[rowp + lane + 64] = d1 * s1 * rstd + f1;
        }
    }
}

extern "C" void kernel_launch(void* const* d_in, const int* in_sizes, int n_in,
                              void* d_out, int out_size, void* d_ws, size_t ws_size,
                              hipStream_t stream) {
    const float* feat_in = (const float*)d_in[0];
    const int*   rows    = (const int*)d_in[1];
    const int*   cols    = (const int*)d_in[2];
    const float* vals    = (const float*)d_in[3];
    const float* W       = (const float*)d_in[4];
    const float* bias    = (const float*)d_in[5];
    const float* scale   = (const float*)d_in[6];
    const float* offset  = (const float*)d_in[7];
    float* out = (float*)d_out;

    // ---- workspace layout ----
    char* p = (char*)d_ws;
    float* aggr = (float*)p;   p += (size_t)N_NODES * DIM * 4;            // 25.6 MB
    int2*  perm = (int2*)p;    p += (size_t)N_BUCKETS * BUCKET_CAP * 8;   // 16.0 MB
    int*   gcnt = (int*)p;     p += ((size_t)N_BUCKETS + 64) * 4;

    hipMemsetAsync(gcnt, 0, (size_t)N_BUCKETS * sizeof(int), stream);

    int sb = (N_EDGES + EPB - 1) / EPB;  // 391
    bucket_scatter   <<<sb, 256, 0, stream>>>(rows, cols, vals, gcnt, perm);
    bucket_aggregate3<<<N_BUCKETS * SLICES, 256, 0, stream>>>(perm, gcnt, feat_in, aggr);
    gemm_relu_ln4    <<<1568, 256, 0, stream>>>(aggr, W, bias, scale, offset, out);
}

// Round 6
// 244.625 us; speedup vs baseline: 6.3778x; 1.1817x over previous
//
#include <hip/hip_runtime.h>

#define N_NODES 50000
#define N_EDGES 1600000
#define DIM 128
#define LN_EPS 1e-10f

#define ROWS_PER_BUCKET 64
#define N_BUCKETS ((N_NODES + ROWS_PER_BUCKET - 1) / ROWS_PER_BUCKET)  // 782
#define BUCKET_CAP 2560   // mean 2048, sigma ~45 -> +11 sigma
#define EPB 4096          // edges per scatter block

#define SLICES 4          // aggregate blocks per bucket
#define ROWS_PER_AGG 16   // rows per aggregate block
#define AGG_CAP 768       // entries per 16-row slice: mean 512, sigma 22 -> +11 sigma

// ---------------------------------------------------------------------------
// feat fp32 -> bf16 (RNE).  Halves the 819 MB logical gather volume and
// doubles feat's effective L2 residency (12.8 MB vs 32 MB aggregate L2).
// ---------------------------------------------------------------------------
__device__ __forceinline__ unsigned short f2bf(float x) {
    unsigned u = __float_as_uint(x);
    return (unsigned short)((u + 0x7FFFu + ((u >> 16) & 1u)) >> 16);
}

__global__ __launch_bounds__(256) void convert_bf16(
    const float* __restrict__ f, ushort4* __restrict__ fb)
{
    int i = blockIdx.x * 256 + threadIdx.x;   // 1.6M threads, 4 elems each
    float4 v = ((const float4*)f)[i];
    fb[i] = make_ushort4(f2bf(v.x), f2bf(v.y), f2bf(v.z), f2bf(v.w));
}

// ---------------------------------------------------------------------------
// Bucket scatter: bin edges by row>>6 into fixed-capacity buckets.
// Per block: LDS histogram -> one global atomic per (block,bucket) reserving a
// contiguous run -> write edges into the run (L2 write combining).
// Packed entry: (col | row_local<<16, val).
// ---------------------------------------------------------------------------
__global__ __launch_bounds__(256) void bucket_scatter(
    const int* __restrict__ rows, const int* __restrict__ cols,
    const float* __restrict__ vals, int* __restrict__ gcnt,
    int2* __restrict__ perm)
{
    __shared__ int cnt[N_BUCKETS];
    __shared__ int gbase[N_BUCKETS];
    __shared__ int lcur[N_BUCKETS];
    const int t = threadIdx.x;
    for (int i = t; i < N_BUCKETS; i += 256) { cnt[i] = 0; lcur[i] = 0; }
    __syncthreads();

    const int base = blockIdx.x * EPB;
    for (int k = 0; k < EPB; k += 256) {
        int e = base + k + t;
        if (e < N_EDGES) atomicAdd(&cnt[rows[e] >> 6], 1);
    }
    __syncthreads();

    for (int i = t; i < N_BUCKETS; i += 256) {
        int c = cnt[i];
        gbase[i] = c ? atomicAdd(&gcnt[i], c) : 0;
    }
    __syncthreads();

    for (int k = 0; k < EPB; k += 256) {
        int e = base + k + t;
        if (e < N_EDGES) {
            int r = rows[e];
            int b = r >> 6;
            int rank = atomicAdd(&lcur[b], 1);
            int pos = gbase[b] + rank;
            if (pos < BUCKET_CAP)   // statistically impossible; safety only
                perm[(size_t)b * BUCKET_CAP + pos] =
                    make_int2(cols[e] | ((r & 63) << 16), __float_as_int(vals[e]));
        }
    }
}

// ---------------------------------------------------------------------------
// Aggregate v4: SLICES blocks per bucket, 16 rows each (3128 blocks).
// Phase 1: count + serial scan + compact slice's entries into a flat LDS
// list.  Phase 2: each wave aggregates 4 rows with fp32 register
// accumulators; bf16 gathers (1 uint = 2 feats per lane), unroll-8 ILP.
// ---------------------------------------------------------------------------
__global__ __launch_bounds__(256) void bucket_aggregate4(
    const int2* __restrict__ perm, const int* __restrict__ gcnt,
    const unsigned short* __restrict__ featb, float* __restrict__ aggr)
{
    __shared__ int  lcnt[ROWS_PER_AGG];
    __shared__ int  rowoff[ROWS_PER_AGG];
    __shared__ int  cursor[ROWS_PER_AGG];
    __shared__ int2 lists[AGG_CAP];          // 6 KB
    const int b     = blockIdx.x >> 2;       // bucket
    const int slice = blockIdx.x & 3;
    const int t = threadIdx.x;
    if (t < ROWS_PER_AGG) lcnt[t] = 0;
    __syncthreads();

    int n = gcnt[b];
    if (n > BUCKET_CAP) n = BUCKET_CAP;
    const int2* pb = perm + (size_t)b * BUCKET_CAP;
    const int lo = slice * ROWS_PER_AGG;

    for (int e = t; e < n; e += 256) {
        int rl = ((pb[e].x >> 16) & 63) - lo;
        if ((unsigned)rl < ROWS_PER_AGG) atomicAdd(&lcnt[rl], 1);
    }
    __syncthreads();
    if (t == 0) {
        int s = 0;
        #pragma unroll
        for (int i = 0; i < ROWS_PER_AGG; ++i) { rowoff[i] = s; cursor[i] = s; s += lcnt[i]; }
    }
    __syncthreads();
    for (int e = t; e < n; e += 256) {
        int2 p = pb[e];
        int rl = ((p.x >> 16) & 63) - lo;
        if ((unsigned)rl < ROWS_PER_AGG) {
            int pos = atomicAdd(&cursor[rl], 1);
            if (pos < AGG_CAP)
                lists[pos] = make_int2(p.x & 0xFFFF, p.y);
        }
    }
    __syncthreads();

    const int lane = t & 63;
    const int wid  = t >> 6;

    #pragma unroll
    for (int i = 0; i < 4; ++i) {
        int rl = wid * 4 + i;
        int r  = b * ROWS_PER_BUCKET + lo + rl;
        int cnt = lcnt[rl];
        int off = rowoff[rl];
        if (off + cnt > AGG_CAP) cnt = AGG_CAP - off;   // safety only
        const int2* L = &lists[off];

        float ax = 0.0f, ay = 0.0f;
        int e = 0;
        for (; e + 7 < cnt; e += 8) {
            int2 p[8];
            unsigned g[8];
            #pragma unroll
            for (int k = 0; k < 8; ++k) p[k] = L[e + k];
            #pragma unroll
            for (int k = 0; k < 8; ++k)
                g[k] = ((const unsigned*)(featb + (size_t)p[k].x * DIM))[lane];
            #pragma unroll
            for (int k = 0; k < 8; ++k) {
                float v  = __int_as_float(p[k].y);
                float fx = __uint_as_float(g[k] << 16);
                float fy = __uint_as_float(g[k] & 0xFFFF0000u);
                ax = fmaf(v, fx, ax);  ay = fmaf(v, fy, ay);
            }
        }
        for (; e < cnt; ++e) {
            int2 p = L[e];
            unsigned g = ((const unsigned*)(featb + (size_t)p.x * DIM))[lane];
            float v  = __int_as_float(p.y);
            float fx = __uint_as_float(g << 16);
            float fy = __uint_as_float(g & 0xFFFF0000u);
            ax = fmaf(v, fx, ax);  ay = fmaf(v, fy, ay);
        }
        if (r < N_NODES)
            ((float2*)(aggr + (size_t)r * DIM))[lane] = make_float2(ax, ay);
    }
}

// ---------------------------------------------------------------------------
// Fused  out = LN(ReLU(aggr @ W^T + b)) * scale + offset.
// 4 nodes per wave per iteration (each LDS W-read feeds 8 FMAs).
// ---------------------------------------------------------------------------
__global__ __launch_bounds__(256) void gemm_relu_ln4(
    const float* __restrict__ aggr, const float* __restrict__ W,
    const float* __restrict__ bias, const float* __restrict__ scale,
    const float* __restrict__ offset, float* __restrict__ out)
{
    __shared__ float sWt[DIM * 129];  // sWt[i*129 + o] = W[o][i]

    for (int idx = threadIdx.x; idx < DIM * DIM; idx += 256) {
        int o = idx >> 7;
        int i = idx & 127;
        sWt[i * 129 + o] = W[idx];
    }
    __syncthreads();

    const int lane = threadIdx.x & 63;
    const int wid  = threadIdx.x >> 6;

    const float b0 = bias[lane],    b1 = bias[lane + 64];
    const float s0 = scale[lane],   s1 = scale[lane + 64];
    const float f0 = offset[lane],  f1 = offset[lane + 64];

    for (int g = blockIdx.x * 16 + wid * 4; g < N_NODES; g += gridDim.x * 16) {
        int nu = __builtin_amdgcn_readfirstlane(g);
        const float* A0 = aggr + (size_t)nu * DIM;
        const float* A1 = A0 + DIM;
        const float* A2 = A1 + DIM;
        const float* A3 = A2 + DIM;

        float x0 = b0, y0 = b1, x1 = b0, y1 = b1;
        float x2 = b0, y2 = b1, x3 = b0, y3 = b1;
        #pragma unroll 8
        for (int i = 0; i < DIM; ++i) {
            float w0 = sWt[i * 129 + lane];
            float w1 = sWt[i * 129 + lane + 64];
            float a0 = A0[i], a1 = A1[i], a2 = A2[i], a3 = A3[i];
            x0 = fmaf(a0, w0, x0);  y0 = fmaf(a0, w1, y0);
            x1 = fmaf(a1, w0, x1);  y1 = fmaf(a1, w1, y1);
            x2 = fmaf(a2, w0, x2);  y2 = fmaf(a2, w1, y2);
            x3 = fmaf(a3, w0, x3);  y3 = fmaf(a3, w1, y3);
        }

        #pragma unroll
        for (int j = 0; j < 4; ++j) {
            float a0 = (j == 0) ? x0 : (j == 1) ? x1 : (j == 2) ? x2 : x3;
            float a1 = (j == 0) ? y0 : (j == 1) ? y1 : (j == 2) ? y2 : y3;
            a0 = fmaxf(a0, 0.0f);
            a1 = fmaxf(a1, 0.0f);

            float s = a0 + a1;
            #pragma unroll
            for (int off = 32; off >= 1; off >>= 1) s += __shfl_xor(s, off, 64);
            float mean = s * (1.0f / 128.0f);

            float d0 = a0 - mean, d1 = a1 - mean;
            float q = d0 * d0 + d1 * d1;
            #pragma unroll
            for (int off = 32; off >= 1; off >>= 1) q += __shfl_xor(q, off, 64);
            float rstd = rsqrtf(q * (1.0f / 128.0f) + LN_EPS);

            size_t rowp = (size_t)(nu + j) * DIM;
            out[rowp + lane]      = d0 * s0 * rstd + f0;
            out[rowp + lane + 64] = d1 * s1 * rstd + f1;
        }
    }
}

extern "C" void kernel_launch(void* const* d_in, const int* in_sizes, int n_in,
                              void* d_out, int out_size, void* d_ws, size_t ws_size,
                              hipStream_t stream) {
    const float* feat_in = (const float*)d_in[0];
    const int*   rows    = (const int*)d_in[1];
    const int*   cols    = (const int*)d_in[2];
    const float* vals    = (const float*)d_in[3];
    const float* W       = (const float*)d_in[4];
    const float* bias    = (const float*)d_in[5];
    const float* scale   = (const float*)d_in[6];
    const float* offset  = (const float*)d_in[7];
    float* out = (float*)d_out;

    // ---- workspace layout ----
    char* p = (char*)d_ws;
    float* aggr = (float*)p;              p += (size_t)N_NODES * DIM * 4;            // 25.6 MB
    int2*  perm = (int2*)p;               p += (size_t)N_BUCKETS * BUCKET_CAP * 8;   // 16.0 MB
    unsigned short* featb = (unsigned short*)p;
                                          p += (size_t)N_NODES * DIM * 2;            // 12.8 MB
    int*   gcnt = (int*)p;                p += ((size_t)N_BUCKETS + 64) * 4;

    hipMemsetAsync(gcnt, 0, (size_t)N_BUCKETS * sizeof(int), stream);

    convert_bf16<<<(N_NODES * DIM / 4) / 256, 256, 0, stream>>>(feat_in, (ushort4*)featb);

    int sb = (N_EDGES + EPB - 1) / EPB;  // 391
    bucket_scatter   <<<sb, 256, 0, stream>>>(rows, cols, vals, gcnt, perm);
    bucket_aggregate4<<<N_BUCKETS * SLICES, 256, 0, stream>>>(perm, gcnt, featb, aggr);
    gemm_relu_ln4    <<<1568, 256, 0, stream>>>(aggr, W, bias, scale, offset, out);
}

// Round 7
// 223.091 us; speedup vs baseline: 6.9934x; 1.0965x over previous
//
#include <hip/hip_runtime.h>

typedef unsigned int uint;

#define N_NODES 50000
#define N_EDGES 1600000
#define DIM 128
#define LN_EPS 1e-10f

#define ROWS_PER_BUCKET 64
#define N_BUCKETS 782            // ceil(50000/64)
#define BUCKET_CAP 2560          // mean 2048, +11 sigma
#define EPB 4096                 // edges per scatter block
#define SB 391                   // scatter blocks  (391*4096 >= 1.6M)
#define FCB 6250                 // feat-convert blocks (1.6M float4 / 256)
#define AGG_LIST_CAP 2048        // int2 entries in the 16 KB LDS union

__device__ __forceinline__ uint f2bf(float x) {
    uint u = __float_as_uint(x);
    return (u + 0x7FFFu + ((u >> 16) & 1u)) >> 16;   // RNE to bf16
}

// ---------------------------------------------------------------------------
// prep = bucket_scatter (blocks [0,SB)) + feat->bf16 convert (blocks
// [SB,SB+FCB)) + W pack (last block), fused so convert's streaming overlaps
// scatter's atomic latency.  Scatter: LDS histogram + row-stash -> one global
// atomic per (block,bucket) reserving a contiguous run (rotated start to
// spread same-line gcnt atomics) -> clustered perm writes.
// Wpk layout: uint[(g*64+l)*4+k] = bf16(W[l][4g+k]) | bf16(W[l+64][4g+k])<<16.
// ---------------------------------------------------------------------------
__global__ __launch_bounds__(256) void prep(
    const float* __restrict__ feat, const float* __restrict__ W,
    const int* __restrict__ rows, const int* __restrict__ cols,
    const float* __restrict__ vals, int* __restrict__ gcnt,
    int2* __restrict__ perm, uint* __restrict__ featb_u,
    uint* __restrict__ wpk_u)
{
    __shared__ int cnt[N_BUCKETS];
    __shared__ int gbase[N_BUCKETS];
    __shared__ int lcur[N_BUCKETS];
    __shared__ int stash[EPB];          // row id per edge (16 KB)
    const int bx = blockIdx.x;
    const int t  = threadIdx.x;

    if (bx >= SB) {
        int cb = bx - SB;
        if (cb < FCB) {                 // feat fp32 -> packed bf16
            int i = cb * 256 + t;       // float4 index
            float4 v = ((const float4*)feat)[i];
            ((uint2*)featb_u)[i] = make_uint2(
                f2bf(v.x) | (f2bf(v.y) << 16),
                f2bf(v.z) | (f2bf(v.w) << 16));
        } else {                        // W pack (one block)
            for (int idx = t; idx < 8192; idx += 256) {
                int g = idx >> 8, rem = idx & 255;
                int l = rem >> 2, k = rem & 3, i = 4 * g + k;
                wpk_u[idx] = f2bf(W[l * DIM + i]) |
                             (f2bf(W[(l + 64) * DIM + i]) << 16);
            }
        }
        return;
    }

    for (int i = t; i < N_BUCKETS; i += 256) { cnt[i] = 0; lcur[i] = 0; }
    __syncthreads();

    const int base = bx * EPB;
    for (int k = 0; k < EPB; k += 256) {
        int e = base + k + t;
        int r = (e < N_EDGES) ? rows[e] : -1;
        stash[k + t] = r;
        if (r >= 0) atomicAdd(&cnt[r >> 6], 1);
    }
    __syncthreads();

    const int rot = (bx * 197) % N_BUCKETS;   // spread same-line gcnt atomics
    for (int i = t; i < N_BUCKETS; i += 256) {
        int j = i + rot; if (j >= N_BUCKETS) j -= N_BUCKETS;
        int c = cnt[j];
        gbase[j] = c ? atomicAdd(&gcnt[j], c) : 0;
    }
    __syncthreads();

    for (int k = 0; k < EPB; k += 256) {
        int e = base + k + t;
        int r = stash[k + t];
        if (r >= 0) {
            int b = r >> 6;
            int rank = atomicAdd(&lcur[b], 1);
            int pos = gbase[b] + rank;
            if (pos < BUCKET_CAP)       // statistically impossible; safety
                perm[(size_t)b * BUCKET_CAP + pos] =
                    make_int2(cols[e] | ((r & 63) << 16), __float_as_int(vals[e]));
        }
    }
}

// ---------------------------------------------------------------------------
// agg_fused: 2 blocks per bucket (512 thr, 32 rows each; grid 1564).
// Phase 1: compact the slice's edges into a flat LDS list (2 coalesced passes).
// Phase 2: 4 rows/wave, bf16 gathers with unroll-8 ILP, fp32 reg accumulators.
// Phase 3: rows regs -> LDS (overlaying the dead lists).
// Phase 4: 128x128 linear (bf16 W from 32 KB LDS, uint4 reads) + ReLU + LN,
// direct store to out.  Kills the aggr round-trip and the gemm dispatch.
// LDS 48.4 KB -> 3 blocks/CU = 24 waves/CU.
// ---------------------------------------------------------------------------
__global__ __launch_bounds__(512, 6) void agg_fused(
    const int2* __restrict__ perm, const int* __restrict__ gcnt,
    const unsigned short* __restrict__ featb, const uint4* __restrict__ wpk,
    const float* __restrict__ bias, const float* __restrict__ scale,
    const float* __restrict__ offset, float* __restrict__ out)
{
    __shared__ float4 un4[1024];   // 16 KB: int2 lists, then 32x128 rowsbuf
    __shared__ uint4  sW[2048];    // 32 KB packed-bf16 W
    __shared__ int lcnt[32], rowoff[32], cursor[32];

    const int t = threadIdx.x;
    for (int i = t; i < 2048; i += 512) sW[i] = wpk[i];

    int2*  lists   = (int2*)un4;
    float* rowsbuf = (float*)un4;

    const int b  = blockIdx.x >> 1;
    const int lo = (blockIdx.x & 1) * 32;
    if (t < 32) lcnt[t] = 0;
    __syncthreads();

    int n = gcnt[b];
    if (n > BUCKET_CAP) n = BUCKET_CAP;
    const int2* pb = perm + (size_t)b * BUCKET_CAP;

    for (int e = t; e < n; e += 512) {
        int rl = ((pb[e].x >> 16) & 63) - lo;
        if ((uint)rl < 32u) atomicAdd(&lcnt[rl], 1);
    }
    __syncthreads();
    if (t == 0) {
        int s = 0;
        #pragma unroll
        for (int i = 0; i < 32; ++i) { rowoff[i] = s; cursor[i] = s; s += lcnt[i]; }
    }
    __syncthreads();
    for (int e = t; e < n; e += 512) {
        int2 p = pb[e];
        int rl = ((p.x >> 16) & 63) - lo;
        if ((uint)rl < 32u) {
            int pos = atomicAdd(&cursor[rl], 1);
            if (pos < AGG_LIST_CAP)
                lists[pos] = make_int2(p.x & 0xFFFF, p.y);
        }
    }
    __syncthreads();

    const int lane = t & 63;
    const int wid  = t >> 6;        // 0..7
    const int rb   = wid * 4;       // this wave's first local row

    float ax[4], ay[4];
    #pragma unroll
    for (int j = 0; j < 4; ++j) {
        int rl = rb + j;
        int cnt = lcnt[rl];
        int off = rowoff[rl];
        if (off + cnt > AGG_LIST_CAP) cnt = AGG_LIST_CAP - off;  // safety
        const int2* L = &lists[off];
        float sx = 0.f, sy = 0.f;
        int e = 0;
        for (; e + 7 < cnt; e += 8) {
            int2 p[8]; uint g[8];
            #pragma unroll
            for (int k = 0; k < 8; ++k) p[k] = L[e + k];
            #pragma unroll
            for (int k = 0; k < 8; ++k)
                g[k] = ((const uint*)(featb + (size_t)p[k].x * DIM))[lane];
            #pragma unroll
            for (int k = 0; k < 8; ++k) {
                float v = __int_as_float(p[k].y);
                sx = fmaf(v, __uint_as_float(g[k] << 16), sx);
                sy = fmaf(v, __uint_as_float(g[k] & 0xFFFF0000u), sy);
            }
        }
        for (; e < cnt; ++e) {
            int2 p = L[e];
            uint g = ((const uint*)(featb + (size_t)p.x * DIM))[lane];
            float v = __int_as_float(p.y);
            sx = fmaf(v, __uint_as_float(g << 16), sx);
            sy = fmaf(v, __uint_as_float(g & 0xFFFF0000u), sy);
        }
        ax[j] = sx; ay[j] = sy;
    }
    __syncthreads();               // all lists reads done -> reuse as rowsbuf

    #pragma unroll
    for (int j = 0; j < 4; ++j)
        ((float2*)rowsbuf)[(rb + j) * 64 + lane] = make_float2(ax[j], ay[j]);
    __syncthreads();

    // ---- phase 4: linear + ReLU + LN for this wave's 4 rows ----
    const float bb0 = bias[lane],   bb1 = bias[lane + 64];
    const float sc0 = scale[lane],  sc1 = scale[lane + 64];
    const float of0 = offset[lane], of1 = offset[lane + 64];

    const float4* R0 = (const float4*)(rowsbuf + (rb + 0) * DIM);
    const float4* R1 = (const float4*)(rowsbuf + (rb + 1) * DIM);
    const float4* R2 = (const float4*)(rowsbuf + (rb + 2) * DIM);
    const float4* R3 = (const float4*)(rowsbuf + (rb + 3) * DIM);

    float x0 = bb0, y0 = bb1, x1 = bb0, y1 = bb1;
    float x2 = bb0, y2 = bb1, x3 = bb0, y3 = bb1;

    #pragma unroll 8
    for (int g = 0; g < 32; ++g) {
        uint4 wv = sW[g * 64 + lane];
        float4 a0 = R0[g], a1 = R1[g], a2 = R2[g], a3 = R3[g];
        float w0, w1;
        w0 = __uint_as_float(wv.x << 16); w1 = __uint_as_float(wv.x & 0xFFFF0000u);
        x0 = fmaf(a0.x, w0, x0);  y0 = fmaf(a0.x, w1, y0);
        x1 = fmaf(a1.x, w0, x1);  y1 = fmaf(a1.x, w1, y1);
        x2 = fmaf(a2.x, w0, x2);  y2 = fmaf(a2.x, w1, y2);
        x3 = fmaf(a3.x, w0, x3);  y3 = fmaf(a3.x, w1, y3);
        w0 = __uint_as_float(wv.y << 16); w1 = __uint_as_float(wv.y & 0xFFFF0000u);
        x0 = fmaf(a0.y, w0, x0);  y0 = fmaf(a0.y, w1, y0);
        x1 = fmaf(a1.y, w0, x1);  y1 = fmaf(a1.y, w1, y1);
        x2 = fmaf(a2.y, w0, x2);  y2 = fmaf(a2.y, w1, y2);
        x3 = fmaf(a3.y, w0, x3);  y3 = fmaf(a3.y, w1, y3);
        w0 = __uint_as_float(wv.z << 16); w1 = __uint_as_float(wv.z & 0xFFFF0000u);
        x0 = fmaf(a0.z, w0, x0);  y0 = fmaf(a0.z, w1, y0);
        x1 = fmaf(a1.z, w0, x1);  y1 = fmaf(a1.z, w1, y1);
        x2 = fmaf(a2.z, w0, x2);  y2 = fmaf(a2.z, w1, y2);
        x3 = fmaf(a3.z, w0, x3);  y3 = fmaf(a3.z, w1, y3);
        w0 = __uint_as_float(wv.w << 16); w1 = __uint_as_float(wv.w & 0xFFFF0000u);
        x0 = fmaf(a0.w, w0, x0);  y0 = fmaf(a0.w, w1, y0);
        x1 = fmaf(a1.w, w0, x1);  y1 = fmaf(a1.w, w1, y1);
        x2 = fmaf(a2.w, w0, x2);  y2 = fmaf(a2.w, w1, y2);
        x3 = fmaf(a3.w, w0, x3);  y3 = fmaf(a3.w, w1, y3);
    }

    #pragma unroll
    for (int j = 0; j < 4; ++j) {
        int r = b * ROWS_PER_BUCKET + lo + rb + j;
        if (r >= N_NODES) continue;                       // wave-uniform
        float A0 = (j == 0) ? x0 : (j == 1) ? x1 : (j == 2) ? x2 : x3;
        float A1 = (j == 0) ? y0 : (j == 1) ? y1 : (j == 2) ? y2 : y3;
        A0 = fmaxf(A0, 0.0f);
        A1 = fmaxf(A1, 0.0f);

        float s = A0 + A1;
        #pragma unroll
        for (int off = 32; off >= 1; off >>= 1) s += __shfl_xor(s, off, 64);
        float mean = s * (1.0f / 128.0f);

        float d0 = A0 - mean, d1 = A1 - mean;
        float q = d0 * d0 + d1 * d1;
        #pragma unroll
        for (int off = 32; off >= 1; off >>= 1) q += __shfl_xor(q, off, 64);
        float rstd = rsqrtf(q * (1.0f / 128.0f) + LN_EPS);

        size_t rowp = (size_t)r * DIM;
        out[rowp + lane]      = d0 * sc0 * rstd + of0;
        out[rowp + lane + 64] = d1 * sc1 * rstd + of1;
    }
}

extern "C" void kernel_launch(void* const* d_in, const int* in_sizes, int n_in,
                              void* d_out, int out_size, void* d_ws, size_t ws_size,
                              hipStream_t stream) {
    const float* feat_in = (const float*)d_in[0];
    const int*   rows    = (const int*)d_in[1];
    const int*   cols    = (const int*)d_in[2];
    const float* vals    = (const float*)d_in[3];
    const float* W       = (const float*)d_in[4];
    const float* bias    = (const float*)d_in[5];
    const float* scale   = (const float*)d_in[6];
    const float* offset  = (const float*)d_in[7];
    float* out = (float*)d_out;

    // ---- workspace layout ----
    char* p = (char*)d_ws;
    int2* perm = (int2*)p;                 p += (size_t)N_BUCKETS * BUCKET_CAP * 8; // 16.0 MB
    unsigned short* featb = (unsigned short*)p;
                                           p += (size_t)N_NODES * DIM * 2;          // 12.8 MB
    uint* wpk = (uint*)p;                  p += 32768;                              // 32 KB
    int*  gcnt = (int*)p;                  p += 4096;

    hipMemsetAsync(gcnt, 0, N_BUCKETS * sizeof(int), stream);

    prep<<<SB + FCB + 1, 256, 0, stream>>>(feat_in, W, rows, cols, vals,
                                           gcnt, perm, (uint*)featb, wpk);
    agg_fused<<<N_BUCKETS * 2, 512, 0, stream>>>(perm, gcnt, featb,
                                                 (const uint4*)wpk,
                                                 bias, scale, offset, out);
}